// Round 3
// baseline (1181.544 us; speedup 1.0000x reference)
//
#include <hip/hip_runtime.h>

// GCN_88734024335852 — 2-layer GCN on MI355X
//
// R14: delete k_csr2 + ebuf2. Aggregation is commutative, so the agg kernels
// consume bucket-granular ebufP directly: one block per 256-node bucket,
// LDS accumulator acc[16][257] (bank=(j+c)%32) fed by ds_add_f32; epilogue
// fused as before. Saves 51MB HBM (ebuf2 w+r), 12.8M sort-side atomics, one
// kernel launch, and the per-node CSR pointer-chase. deg is computed by
// fire-and-forget global atomics fused into sortplace; dinv = rsqrt(deg+1)
// inline at each consumer (dinv array removed).
//
//   dinv[i] = rsqrt(deg_in[i]+1)
//   layer out[c] = dinv[c] * ( g[c] + sum_{col[e]==c} g[row[e]] ) + b
//   g[i] = (h[i] @ W) * dinv[i]
//
// ws (floats): xe[n] g[16n] g2[n] gbuf[8n] deg[n] gcur[nb*16] ebufP[nb*CAP]
//              (~38 MB)

#define D_FEAT 128
#define HIDDEN 16
#define TILE 4096
#define CAP 17408u

__device__ inline float bf2f(unsigned short u) {
    union { unsigned x; float f; } t; t.x = ((unsigned)u) << 16; return t.f;
}

__global__ __launch_bounds__(256) void k_init(float* xe, unsigned* deg, unsigned* gcur,
                                              int n, int nb) {
    int t = blockIdx.x * 256 + threadIdx.x;
    if (t < n) { xe[t] = 0.f; deg[t] = 0u; }
    if (t < nb) gcur[t * 16] = (unsigned)t * CAP;
}

// Fused: load row/col/ea; deg global atomics (fire-and-forget); xe wave
// segmented scan (rows sorted); LDS bucket hist; wave-based block scan
// (2 barriers); claim padded-bucket regions; stage bucket-ordered in LDS;
// coalesced run writes.
__global__ __launch_bounds__(512) void k_sortplace(const int* __restrict__ row,
                                                   const int* __restrict__ col,
                                                   const float* __restrict__ ea,
                                                   float* __restrict__ xe,
                                                   unsigned* __restrict__ deg,
                                                   unsigned* __restrict__ gcur,
                                                   unsigned* __restrict__ ebufP,
                                                   int ne, int nb) {
    __shared__ unsigned stage[TILE];
    __shared__ unsigned short sbuck[TILE];
    __shared__ unsigned h[512], base_[512], cursor[512], gb_[512];
    __shared__ unsigned wsum[8];
    int tid = threadIdx.x;
    int lane = tid & 63;
    int w = tid >> 6;
    int tile0 = blockIdx.x * TILE;
    int cnt_t = min(TILE, ne - tile0);
    h[tid] = 0u;
    __syncthreads();
    int rr[8], cc[8];
    float aa[8];
    #pragma unroll
    for (int k = 0; k < 8; ++k) {
        int e = tile0 + tid + k * 512;
        if (e < ne) {
            rr[k] = row[e]; cc[k] = col[e]; aa[k] = ea[e];
            atomicAdd(&h[cc[k] >> 8], 1u);
            atomicAdd(&deg[cc[k]], 1u);      // no-return global atomic
        } else { rr[k] = -1; cc[k] = 0; aa[k] = 0.f; }
    }
    // xe segmented scan per 64-edge wave window (rows sorted globally).
    #pragma unroll
    for (int k = 0; k < 8; ++k) {
        int r = rr[k];
        float a = aa[k];
        #pragma unroll
        for (int d = 1; d < 64; d <<= 1) {
            float up = __shfl_up(a, d);
            int  rup = __shfl_up(r, d);
            if (lane >= d && rup == r) a += up;
        }
        int rdn = __shfl_down(r, 1);
        bool tail = (lane == 63) || (rdn != r);
        if (r >= 0 && tail) unsafeAtomicAdd(&xe[r], a);
    }
    __syncthreads();
    // Wave-level inclusive scan of h[512] -> exclusive prefix, 2 barriers.
    unsigned hv = h[tid];
    unsigned s = hv;
    #pragma unroll
    for (int d = 1; d < 64; d <<= 1) {
        unsigned u = __shfl_up(s, d);
        if (lane >= d) s += u;
    }
    if (lane == 63) wsum[w] = s;
    __syncthreads();
    unsigned woff = 0;
    #pragma unroll
    for (int i = 0; i < 8; ++i) woff += (i < w) ? wsum[i] : 0u;
    unsigned ex = s + woff - hv;
    base_[tid] = ex;
    cursor[tid] = ex;
    if (tid < nb && hv) gb_[tid] = atomicAdd(&gcur[tid * 16], hv);
    __syncthreads();
    #pragma unroll
    for (int k = 0; k < 8; ++k) {
        if (rr[k] >= 0) {
            int b = cc[k] >> 8;
            unsigned p = atomicAdd(&cursor[b], 1u);
            stage[p] = (((unsigned)(cc[k] & 255)) << 24) | (unsigned)rr[k];
            sbuck[p] = (unsigned short)b;
        }
    }
    __syncthreads();
    for (int t = tid; t < cnt_t; t += 512) {
        unsigned b = sbuck[t];
        unsigned pos = gb_[b] + ((unsigned)t - base_[b]);
        if (pos < (b + 1u) * CAP) ebufP[pos] = stage[t];
    }
}

// g[i][j] = (sum_k x[i][k]*W1[k][j] + xe[i]*W1[128][j]) * rsqrt(deg[i]+1)
// W transposed in LDS (stride 132) -> b128 weight reads.
// Writes fp32 g (self-term) and bf16 gbuf (gather copy, RNE).
__global__ __launch_bounds__(256) void k_gemm1(const float* __restrict__ x,
                                               const float* __restrict__ xe,
                                               const unsigned* __restrict__ deg,
                                               const float* __restrict__ W1,
                                               float* __restrict__ g,
                                               unsigned short* __restrict__ gb, int n) {
    __shared__ float WsT[16 * 132];   // WsT[j*132 + k] = W1[k*16 + j], k=0..128
    __shared__ float xs[64 * 132];
    int tid = threadIdx.x;
    for (int idx = tid; idx < 129 * 16; idx += 256) {
        int k = idx >> 4, j = idx & 15;
        WsT[j * 132 + k] = W1[idx];
    }
    int n0 = blockIdx.x * 64;
    const float4* x4 = (const float4*)x;
    for (int idx = tid; idx < 64 * 32; idx += 256) {
        int r = idx >> 5, c = idx & 31;
        float4 v = (n0 + r < n) ? x4[(size_t)(n0 + r) * 32 + c]
                                : make_float4(0.f, 0.f, 0.f, 0.f);
        *(float4*)&xs[r * 132 + c * 4] = v;
    }
    if (tid < 64) {
        int r = tid;
        xs[r * 132 + 128] = (n0 + r < n) ? xe[n0 + r] : 0.f;
    }
    __syncthreads();
    int j  = tid & 15;
    int nb = tid >> 4;
    const float* wrow = &WsT[j * 132];
    for (int rep = 0; rep < 4; ++rep) {
        int nl = nb + (rep << 4);
        int node = n0 + nl;
        const float* xrow = &xs[nl * 132];
        float acc = 0.f;
        #pragma unroll
        for (int k = 0; k < 128; k += 4) {
            float4 xv = *(const float4*)&xrow[k];
            float4 wv = *(const float4*)&wrow[k];
            acc += xv.x * wv.x;
            acc += xv.y * wv.y;
            acc += xv.z * wv.z;
            acc += xv.w * wv.w;
        }
        acc += xrow[128] * wrow[128];
        if (node < n) {
            float v = acc * rsqrtf((float)deg[node] + 1.0f);
            g[(size_t)node * 16 + j] = v;
            union { float f; unsigned u; } cv; cv.f = v;
            unsigned r16 = (cv.u + 0x7FFFu + ((cv.u >> 16) & 1u)) >> 16;
            gb[(size_t)node * 16 + j] = (unsigned short)r16;
        }
    }
}

// Layer-1 agg per bucket: block owns 256 nodes; edges consumed in arbitrary
// order from ebufP. 4 lanes/edge: lane u gathers uint2 (features 4u..4u+3 as
// bf16 pairs) and ds_add_f32 into acc[16][257] (bank=(j+c)%32). Fused
// epilogue: relu(dinv*(g+acc)+b1) dot W2, * dinv -> g2.
__global__ __launch_bounds__(512) void k_agg1b(const unsigned* __restrict__ gcur,
                                               const unsigned* __restrict__ ebufP,
                                               const unsigned* __restrict__ gu,
                                               const float* __restrict__ g,
                                               const unsigned* __restrict__ deg,
                                               const float* __restrict__ b1,
                                               const float* __restrict__ W2,
                                               float* __restrict__ g2, int n) {
    __shared__ float acc[16][257];
    int tid = threadIdx.x, b = blockIdx.x;
    for (int idx = tid; idx < 16 * 257; idx += 512) ((float*)acc)[idx] = 0.f;
    __syncthreads();
    unsigned base = (unsigned)b * CAP;
    unsigned m = min(gcur[b * 16] - base, CAP);
    const uint2* gu2 = (const uint2*)gu;
    int u = tid & 3;
    int j0 = u * 4;
    unsigned e = (unsigned)(tid >> 2);
    for (; e + 128 < m; e += 256) {
        unsigned pk0 = ebufP[base + e];
        unsigned pk1 = ebufP[base + e + 128];
        uint2 w0 = gu2[(size_t)(pk0 & 0xFFFFFFu) * 4 + u];
        uint2 w1 = gu2[(size_t)(pk1 & 0xFFFFFFu) * 4 + u];
        unsigned c0 = pk0 >> 24, c1 = pk1 >> 24;
        unsafeAtomicAdd(&acc[j0    ][c0], bf2f((unsigned short)w0.x));
        unsafeAtomicAdd(&acc[j0 + 1][c0], bf2f((unsigned short)(w0.x >> 16)));
        unsafeAtomicAdd(&acc[j0 + 2][c0], bf2f((unsigned short)w0.y));
        unsafeAtomicAdd(&acc[j0 + 3][c0], bf2f((unsigned short)(w0.y >> 16)));
        unsafeAtomicAdd(&acc[j0    ][c1], bf2f((unsigned short)w1.x));
        unsafeAtomicAdd(&acc[j0 + 1][c1], bf2f((unsigned short)(w1.x >> 16)));
        unsafeAtomicAdd(&acc[j0 + 2][c1], bf2f((unsigned short)w1.y));
        unsafeAtomicAdd(&acc[j0 + 3][c1], bf2f((unsigned short)(w1.y >> 16)));
    }
    for (; e < m; e += 128) {
        unsigned pk = ebufP[base + e];
        uint2 w = gu2[(size_t)(pk & 0xFFFFFFu) * 4 + u];
        unsigned c = pk >> 24;
        unsafeAtomicAdd(&acc[j0    ][c], bf2f((unsigned short)w.x));
        unsafeAtomicAdd(&acc[j0 + 1][c], bf2f((unsigned short)(w.x >> 16)));
        unsafeAtomicAdd(&acc[j0 + 2][c], bf2f((unsigned short)w.y));
        unsafeAtomicAdd(&acc[j0 + 3][c], bf2f((unsigned short)(w.y >> 16)));
    }
    __syncthreads();
    for (int idx = tid; idx < 256 * 16; idx += 512) {
        int c = idx >> 4, j = idx & 15;
        int v = b * 256 + c;
        if (v < n) {
            float di = rsqrtf((float)deg[v] + 1.0f);
            float val = di * (g[(size_t)v * 16 + j] + acc[j][c]) + b1[j];
            val = fmaxf(val, 0.f);
            float prd = val * W2[j];
            prd += __shfl_down(prd, 8, 16);
            prd += __shfl_down(prd, 4, 16);
            prd += __shfl_down(prd, 2, 16);
            prd += __shfl_down(prd, 1, 16);
            if (j == 0) g2[v] = prd * di;
        }
    }
}

// Layer-2 agg per bucket: acc2[256] of g2[row]; fused output epilogue.
__global__ __launch_bounds__(512) void k_agg2b(const unsigned* __restrict__ gcur,
                                               const unsigned* __restrict__ ebufP,
                                               const float* __restrict__ g2,
                                               const unsigned* __restrict__ deg,
                                               const float* __restrict__ b2,
                                               float* __restrict__ out, int n) {
    __shared__ float acc2[256];
    int tid = threadIdx.x, b = blockIdx.x;
    if (tid < 256) acc2[tid] = 0.f;
    __syncthreads();
    unsigned base = (unsigned)b * CAP;
    unsigned m = min(gcur[b * 16] - base, CAP);
    unsigned e = (unsigned)tid;
    for (; e + 512 < m; e += 1024) {
        unsigned pk0 = ebufP[base + e];
        unsigned pk1 = ebufP[base + e + 512];
        float a0 = g2[pk0 & 0xFFFFFFu];
        float a1 = g2[pk1 & 0xFFFFFFu];
        unsafeAtomicAdd(&acc2[pk0 >> 24], a0);
        unsafeAtomicAdd(&acc2[pk1 >> 24], a1);
    }
    for (; e < m; e += 512) {
        unsigned pk = ebufP[base + e];
        unsafeAtomicAdd(&acc2[pk >> 24], g2[pk & 0xFFFFFFu]);
    }
    __syncthreads();
    if (tid < 256) {
        int v = b * 256 + tid;
        if (v < n) {
            float di = rsqrtf((float)deg[v] + 1.0f);
            out[v] = di * (g2[v] + acc2[tid]) + b2[0];
        }
    }
}

extern "C" void kernel_launch(void* const* d_in, const int* in_sizes, int n_in,
                              void* d_out, int out_size, void* d_ws, size_t ws_size,
                              hipStream_t stream) {
    const float* x   = (const float*)d_in[0];
    const float* ea  = (const float*)d_in[1];
    const int*   row = (const int*)d_in[2];
    const int*   col = (const int*)d_in[3];
    const float* W1  = (const float*)d_in[4];
    const float* b1  = (const float*)d_in[5];
    const float* W2  = (const float*)d_in[6];
    const float* b2  = (const float*)d_in[7];
    float* out = (float*)d_out;

    int n  = in_sizes[0] / D_FEAT;   // 100000
    int ne = in_sizes[2];            // 6400000
    int nb = (n + 255) >> 8;         // 391 buckets of 256 nodes

    float* ws   = (float*)d_ws;
    float* xe   = ws;                      // n
    float* g    = ws + (size_t)n;          // 16n
    float* g2   = ws + (size_t)17 * n;     // n
    unsigned short* gbuf = (unsigned short*)(ws + (size_t)18 * n);  // 16n ushort = 8n floats
    unsigned* deg  = (unsigned*)(ws + (size_t)26 * n);  // n
    unsigned* gcur = deg + (size_t)n;                   // nb*16
    unsigned* ebufP = gcur + (size_t)nb * 16;           // nb*CAP

    dim3 blk(256);
    int g_node = (n + 255) / 256;
    int g_tile = (ne + TILE - 1) / TILE;
    int g_gemm = (n + 63) / 64;

    k_init<<<g_node, blk, 0, stream>>>(xe, deg, gcur, n, nb);
    k_sortplace<<<g_tile, 512, 0, stream>>>(row, col, ea, xe, deg, gcur, ebufP, ne, nb);
    k_gemm1<<<g_gemm, blk, 0, stream>>>(x, xe, deg, W1, g, gbuf, n);
    k_agg1b<<<nb, 512, 0, stream>>>(gcur, ebufP, (const unsigned*)gbuf, g, deg, b1, W2, g2, n);
    k_agg2b<<<nb, 512, 0, stream>>>(gcur, ebufP, g2, deg, b2, out, n);
}

// Round 4
// 543.479 us; speedup vs baseline: 2.1740x; 2.1740x over previous
//
#include <hip/hip_runtime.h>

// GCN_88734024335852 — 2-layer GCN on MI355X
//
// R15: R14's float-LDS-atomic agg was pathological (682us/350us at 1% of
// every pipe -> the fp32 LDS atomic path is ~25x slower than ds ops; int
// LDS atomics are fine). Keep csr2 deleted + deg-via-global-atomics, but
// aggregate with the PROVEN pattern: per-bucket LDS sort (deg-scan gives
// start offsets for free; one coalesced ebufP pass scatters rows into
// sorted[CAP] via INT cursor atomics) + agg16g's 16-lane/node register
// walk reading rows from LDS. No float atomics anywhere. Layer 2: same
// prologue, 2-lane/node scalar walk over L2-hot g2.
//
//   dinv[i] = rsqrt(deg_in[i]+1)
//   layer out[c] = dinv[c] * ( g[c] + sum_{col[e]==c} g[row[e]] ) + b
//   g[i] = (h[i] @ W) * dinv[i]
//
// ws (floats): xe[n] g[16n] g2[n] gbuf[8n] deg[n] gcur[nb*16] ebufP[nb*CAP]
//              (~38 MB)

#define D_FEAT 128
#define HIDDEN 16
#define TILE 4096
#define CAP 17408u

__device__ inline float bf2f(unsigned short u) {
    union { unsigned x; float f; } t; t.x = ((unsigned)u) << 16; return t.f;
}

__global__ __launch_bounds__(256) void k_init(float* xe, unsigned* deg, unsigned* gcur,
                                              int n, int nb) {
    int t = blockIdx.x * 256 + threadIdx.x;
    if (t < n) { xe[t] = 0.f; deg[t] = 0u; }
    if (t < nb) gcur[t * 16] = (unsigned)t * CAP;
}

// Fused: load row/col/ea; deg global atomics (fire-and-forget); xe wave
// segmented scan (rows sorted); LDS bucket hist; wave-based block scan
// (2 barriers); claim padded-bucket regions; stage bucket-ordered in LDS;
// coalesced run writes.
__global__ __launch_bounds__(512) void k_sortplace(const int* __restrict__ row,
                                                   const int* __restrict__ col,
                                                   const float* __restrict__ ea,
                                                   float* __restrict__ xe,
                                                   unsigned* __restrict__ deg,
                                                   unsigned* __restrict__ gcur,
                                                   unsigned* __restrict__ ebufP,
                                                   int ne, int nb) {
    __shared__ unsigned stage[TILE];
    __shared__ unsigned short sbuck[TILE];
    __shared__ unsigned h[512], base_[512], cursor[512], gb_[512];
    __shared__ unsigned wsum[8];
    int tid = threadIdx.x;
    int lane = tid & 63;
    int w = tid >> 6;
    int tile0 = blockIdx.x * TILE;
    int cnt_t = min(TILE, ne - tile0);
    h[tid] = 0u;
    __syncthreads();
    int rr[8], cc[8];
    float aa[8];
    #pragma unroll
    for (int k = 0; k < 8; ++k) {
        int e = tile0 + tid + k * 512;
        if (e < ne) {
            rr[k] = row[e]; cc[k] = col[e]; aa[k] = ea[e];
            atomicAdd(&h[cc[k] >> 8], 1u);
            atomicAdd(&deg[cc[k]], 1u);      // no-return global atomic
        } else { rr[k] = -1; cc[k] = 0; aa[k] = 0.f; }
    }
    // xe segmented scan per 64-edge wave window (rows sorted globally).
    #pragma unroll
    for (int k = 0; k < 8; ++k) {
        int r = rr[k];
        float a = aa[k];
        #pragma unroll
        for (int d = 1; d < 64; d <<= 1) {
            float up = __shfl_up(a, d);
            int  rup = __shfl_up(r, d);
            if (lane >= d && rup == r) a += up;
        }
        int rdn = __shfl_down(r, 1);
        bool tail = (lane == 63) || (rdn != r);
        if (r >= 0 && tail) unsafeAtomicAdd(&xe[r], a);
    }
    __syncthreads();
    // Wave-level inclusive scan of h[512] -> exclusive prefix, 2 barriers.
    unsigned hv = h[tid];
    unsigned s = hv;
    #pragma unroll
    for (int d = 1; d < 64; d <<= 1) {
        unsigned u = __shfl_up(s, d);
        if (lane >= d) s += u;
    }
    if (lane == 63) wsum[w] = s;
    __syncthreads();
    unsigned woff = 0;
    #pragma unroll
    for (int i = 0; i < 8; ++i) woff += (i < w) ? wsum[i] : 0u;
    unsigned ex = s + woff - hv;
    base_[tid] = ex;
    cursor[tid] = ex;
    if (tid < nb && hv) gb_[tid] = atomicAdd(&gcur[tid * 16], hv);
    __syncthreads();
    #pragma unroll
    for (int k = 0; k < 8; ++k) {
        if (rr[k] >= 0) {
            int b = cc[k] >> 8;
            unsigned p = atomicAdd(&cursor[b], 1u);
            stage[p] = (((unsigned)(cc[k] & 255)) << 24) | (unsigned)rr[k];
            sbuck[p] = (unsigned short)b;
        }
    }
    __syncthreads();
    for (int t = tid; t < cnt_t; t += 512) {
        unsigned b = sbuck[t];
        unsigned pos = gb_[b] + ((unsigned)t - base_[b]);
        if (pos < (b + 1u) * CAP) ebufP[pos] = stage[t];
    }
}

// g[i][j] = (sum_k x[i][k]*W1[k][j] + xe[i]*W1[128][j]) * rsqrt(deg[i]+1)
// W transposed in LDS (stride 132) -> b128 weight reads.
// Writes fp32 g (self-term) and bf16 gbuf (gather copy, RNE).
__global__ __launch_bounds__(256) void k_gemm1(const float* __restrict__ x,
                                               const float* __restrict__ xe,
                                               const unsigned* __restrict__ deg,
                                               const float* __restrict__ W1,
                                               float* __restrict__ g,
                                               unsigned short* __restrict__ gb, int n) {
    __shared__ float WsT[16 * 132];   // WsT[j*132 + k] = W1[k*16 + j], k=0..128
    __shared__ float xs[64 * 132];
    int tid = threadIdx.x;
    for (int idx = tid; idx < 129 * 16; idx += 256) {
        int k = idx >> 4, j = idx & 15;
        WsT[j * 132 + k] = W1[idx];
    }
    int n0 = blockIdx.x * 64;
    const float4* x4 = (const float4*)x;
    for (int idx = tid; idx < 64 * 32; idx += 256) {
        int r = idx >> 5, c = idx & 31;
        float4 v = (n0 + r < n) ? x4[(size_t)(n0 + r) * 32 + c]
                                : make_float4(0.f, 0.f, 0.f, 0.f);
        *(float4*)&xs[r * 132 + c * 4] = v;
    }
    if (tid < 64) {
        int r = tid;
        xs[r * 132 + 128] = (n0 + r < n) ? xe[n0 + r] : 0.f;
    }
    __syncthreads();
    int j  = tid & 15;
    int nb = tid >> 4;
    const float* wrow = &WsT[j * 132];
    for (int rep = 0; rep < 4; ++rep) {
        int nl = nb + (rep << 4);
        int node = n0 + nl;
        const float* xrow = &xs[nl * 132];
        float acc = 0.f;
        #pragma unroll
        for (int k = 0; k < 128; k += 4) {
            float4 xv = *(const float4*)&xrow[k];
            float4 wv = *(const float4*)&wrow[k];
            acc += xv.x * wv.x;
            acc += xv.y * wv.y;
            acc += xv.z * wv.z;
            acc += xv.w * wv.w;
        }
        acc += xrow[128] * wrow[128];
        if (node < n) {
            float v = acc * rsqrtf((float)deg[node] + 1.0f);
            g[(size_t)node * 16 + j] = v;
            union { float f; unsigned u; } cv; cv.f = v;
            unsigned r16 = (cv.u + 0x7FFFu + ((cv.u >> 16) & 1u)) >> 16;
            gb[(size_t)node * 16 + j] = (unsigned short)r16;
        }
    }
}

// Layer-1 agg per bucket: deg-scan -> per-node start; one ebufP pass
// scatters rows into sorted[] (int LDS cursor atomics); then agg16g's
// 16-lane/node register walk reads rows from LDS; fused epilogue.
__global__ __launch_bounds__(512) void k_agg1s(const unsigned* __restrict__ gcur,
                                               const unsigned* __restrict__ ebufP,
                                               const unsigned* __restrict__ deg,
                                               const unsigned* __restrict__ gu,
                                               const float* __restrict__ g,
                                               const float* __restrict__ b1,
                                               const float* __restrict__ W2,
                                               float* __restrict__ g2, int n) {
    __shared__ unsigned sorted[CAP];
    __shared__ unsigned dg[256], st[256], cur[256];
    __shared__ unsigned wsum[4];
    int tid = threadIdx.x, b = blockIdx.x, lane = tid & 63;
    unsigned base = (unsigned)b * CAP;
    unsigned m = min(gcur[b * 16] - base, CAP);
    unsigned dval = 0, s = 0;
    if (tid < 256) {
        int v = b * 256 + tid;
        dval = (v < n) ? deg[v] : 0u;
        dg[tid] = dval;
        s = dval;
        #pragma unroll
        for (int d = 1; d < 64; d <<= 1) {
            unsigned uu = __shfl_up(s, d);
            if (lane >= d) s += uu;
        }
        if (lane == 63) wsum[tid >> 6] = s;
    }
    __syncthreads();
    if (tid < 256) {
        int w = tid >> 6;
        unsigned woff = 0;
        #pragma unroll
        for (int i = 0; i < 4; ++i) woff += (i < w) ? wsum[i] : 0u;
        unsigned ex = s + woff - dval;
        st[tid] = ex;
        cur[tid] = ex;
    }
    __syncthreads();
    unsigned i = tid;
    for (; i + 1536 < m; i += 2048) {
        unsigned pk0 = ebufP[base + i];
        unsigned pk1 = ebufP[base + i + 512];
        unsigned pk2 = ebufP[base + i + 1024];
        unsigned pk3 = ebufP[base + i + 1536];
        unsigned p0 = atomicAdd(&cur[pk0 >> 24], 1u);
        unsigned p1 = atomicAdd(&cur[pk1 >> 24], 1u);
        unsigned p2 = atomicAdd(&cur[pk2 >> 24], 1u);
        unsigned p3 = atomicAdd(&cur[pk3 >> 24], 1u);
        if (p0 < CAP) sorted[p0] = pk0 & 0xFFFFFFu;
        if (p1 < CAP) sorted[p1] = pk1 & 0xFFFFFFu;
        if (p2 < CAP) sorted[p2] = pk2 & 0xFFFFFFu;
        if (p3 < CAP) sorted[p3] = pk3 & 0xFFFFFFu;
    }
    for (; i < m; i += 512) {
        unsigned pk = ebufP[base + i];
        unsigned p = atomicAdd(&cur[pk >> 24], 1u);
        if (p < CAP) sorted[p] = pk & 0xFFFFFFu;
    }
    __syncthreads();
    int grp = tid >> 4, j16 = tid & 15;
    int u = tid & 7;
    int half = (tid >> 3) & 1;
    float2 bb = ((const float2*)b1)[u];
    float2 ww = ((const float2*)W2)[u];
    for (int it = 0; it < 8; ++it) {
        int c = it * 32 + grp;
        int v = b * 256 + c;
        if (v >= n) break;
        unsigned s0 = st[c], e0 = s0 + dg[c];
        float ax0 = 0.f, ay0 = 0.f, ax1 = 0.f, ay1 = 0.f;
        unsigned q = s0 + half;
        for (; q + 2 < e0; q += 4) {
            unsigned r0 = sorted[q], r1 = sorted[q + 2];
            unsigned w0 = gu[(size_t)r0 * 8 + u];
            unsigned w1 = gu[(size_t)r1 * 8 + u];
            ax0 += bf2f((unsigned short)w0); ay0 += bf2f((unsigned short)(w0 >> 16));
            ax1 += bf2f((unsigned short)w1); ay1 += bf2f((unsigned short)(w1 >> 16));
        }
        if (q < e0) {
            unsigned w0 = gu[(size_t)sorted[q] * 8 + u];
            ax0 += bf2f((unsigned short)w0); ay0 += bf2f((unsigned short)(w0 >> 16));
        }
        float sx = ax0 + ax1, sy = ay0 + ay1;
        sx += __shfl_xor(sx, 8, 16);
        sy += __shfl_xor(sy, 8, 16);
        float di = rsqrtf((float)dg[c] + 1.0f);
        float2 gs = ((const float2*)g)[(size_t)v * 8 + u];
        float vx = fmaxf(di * (gs.x + sx) + bb.x, 0.f);
        float vy = fmaxf(di * (gs.y + sy) + bb.y, 0.f);
        float prd = vx * ww.x + vy * ww.y;
        prd += __shfl_down(prd, 4, 8);
        prd += __shfl_down(prd, 2, 8);
        prd += __shfl_down(prd, 1, 8);
        if (j16 == 0) g2[v] = prd * di;
    }
}

// Layer-2 agg per bucket: same sort prologue; 2-lane/node scalar walk over
// L2-hot g2 gathers; fused output epilogue.
__global__ __launch_bounds__(512) void k_agg2s(const unsigned* __restrict__ gcur,
                                               const unsigned* __restrict__ ebufP,
                                               const unsigned* __restrict__ deg,
                                               const float* __restrict__ g2,
                                               const float* __restrict__ b2,
                                               float* __restrict__ out, int n) {
    __shared__ unsigned sorted[CAP];
    __shared__ unsigned dg[256], st[256], cur[256];
    __shared__ unsigned wsum[4];
    int tid = threadIdx.x, b = blockIdx.x, lane = tid & 63;
    unsigned base = (unsigned)b * CAP;
    unsigned m = min(gcur[b * 16] - base, CAP);
    unsigned dval = 0, s = 0;
    if (tid < 256) {
        int v = b * 256 + tid;
        dval = (v < n) ? deg[v] : 0u;
        dg[tid] = dval;
        s = dval;
        #pragma unroll
        for (int d = 1; d < 64; d <<= 1) {
            unsigned uu = __shfl_up(s, d);
            if (lane >= d) s += uu;
        }
        if (lane == 63) wsum[tid >> 6] = s;
    }
    __syncthreads();
    if (tid < 256) {
        int w = tid >> 6;
        unsigned woff = 0;
        #pragma unroll
        for (int i = 0; i < 4; ++i) woff += (i < w) ? wsum[i] : 0u;
        unsigned ex = s + woff - dval;
        st[tid] = ex;
        cur[tid] = ex;
    }
    __syncthreads();
    unsigned i = tid;
    for (; i + 1536 < m; i += 2048) {
        unsigned pk0 = ebufP[base + i];
        unsigned pk1 = ebufP[base + i + 512];
        unsigned pk2 = ebufP[base + i + 1024];
        unsigned pk3 = ebufP[base + i + 1536];
        unsigned p0 = atomicAdd(&cur[pk0 >> 24], 1u);
        unsigned p1 = atomicAdd(&cur[pk1 >> 24], 1u);
        unsigned p2 = atomicAdd(&cur[pk2 >> 24], 1u);
        unsigned p3 = atomicAdd(&cur[pk3 >> 24], 1u);
        if (p0 < CAP) sorted[p0] = pk0 & 0xFFFFFFu;
        if (p1 < CAP) sorted[p1] = pk1 & 0xFFFFFFu;
        if (p2 < CAP) sorted[p2] = pk2 & 0xFFFFFFu;
        if (p3 < CAP) sorted[p3] = pk3 & 0xFFFFFFu;
    }
    for (; i < m; i += 512) {
        unsigned pk = ebufP[base + i];
        unsigned p = atomicAdd(&cur[pk >> 24], 1u);
        if (p < CAP) sorted[p] = pk & 0xFFFFFFu;
    }
    __syncthreads();
    int c = tid >> 1, half = tid & 1;
    int v = b * 256 + c;
    float a = 0.f;
    unsigned s0 = st[c], e0 = s0 + dg[c];
    unsigned q = s0 + half;
    for (; q + 2 < e0; q += 4) {
        a += g2[sorted[q]];
        a += g2[sorted[q + 2]];
    }
    if (q < e0) a += g2[sorted[q]];
    a += __shfl_xor(a, 1, 2);
    if (half == 0 && v < n) {
        float di = rsqrtf((float)dg[c] + 1.0f);
        out[v] = di * (g2[v] + a) + b2[0];
    }
}

extern "C" void kernel_launch(void* const* d_in, const int* in_sizes, int n_in,
                              void* d_out, int out_size, void* d_ws, size_t ws_size,
                              hipStream_t stream) {
    const float* x   = (const float*)d_in[0];
    const float* ea  = (const float*)d_in[1];
    const int*   row = (const int*)d_in[2];
    const int*   col = (const int*)d_in[3];
    const float* W1  = (const float*)d_in[4];
    const float* b1  = (const float*)d_in[5];
    const float* W2  = (const float*)d_in[6];
    const float* b2  = (const float*)d_in[7];
    float* out = (float*)d_out;

    int n  = in_sizes[0] / D_FEAT;   // 100000
    int ne = in_sizes[2];            // 6400000
    int nb = (n + 255) >> 8;         // 391 buckets of 256 nodes

    float* ws   = (float*)d_ws;
    float* xe   = ws;                      // n
    float* g    = ws + (size_t)n;          // 16n
    float* g2   = ws + (size_t)17 * n;     // n
    unsigned short* gbuf = (unsigned short*)(ws + (size_t)18 * n);  // 16n ushort = 8n floats
    unsigned* deg  = (unsigned*)(ws + (size_t)26 * n);  // n
    unsigned* gcur = deg + (size_t)n;                   // nb*16
    unsigned* ebufP = gcur + (size_t)nb * 16;           // nb*CAP

    dim3 blk(256);
    int g_node = (n + 255) / 256;
    int g_tile = (ne + TILE - 1) / TILE;
    int g_gemm = (n + 63) / 64;

    k_init<<<g_node, blk, 0, stream>>>(xe, deg, gcur, n, nb);
    k_sortplace<<<g_tile, 512, 0, stream>>>(row, col, ea, xe, deg, gcur, ebufP, ne, nb);
    k_gemm1<<<g_gemm, blk, 0, stream>>>(x, xe, deg, W1, g, gbuf, n);
    k_agg1s<<<nb, 512, 0, stream>>>(gcur, ebufP, deg, (const unsigned*)gbuf, g, b1, W2, g2, n);
    k_agg2s<<<nb, 512, 0, stream>>>(gcur, ebufP, deg, g2, b2, out, n);
}

// Round 5
// 293.635 us; speedup vs baseline: 4.0238x; 1.8509x over previous
//
#include <hip/hip_runtime.h>

// GCN_88734024335852 — 2-layer GCN on MI355X
//
// R16: R15's deg-via-global-atomics poisoned sortplace (+240us, +198MB
// write: scattered device-scope atomics resolve at the memory-side
// coherence point). Fix: sortplace reverts to the verified 68.5us form;
// deg comes from k_deghist = per-bucket LDS INT histogram over ebufP
// (csr2's proven pattern), coalesced deg write. Also: agg1s gather is now
// uint2 (4 lanes/edge x 8B, layout verified in R14) -> half the L2
// requests, 4-way edge ILP.
//
//   dinv[i] = rsqrt(deg_in[i]+1)
//   layer out[c] = dinv[c] * ( g[c] + sum_{col[e]==c} g[row[e]] ) + b
//   g[i] = (h[i] @ W) * dinv[i]
//
// ws (floats): xe[n] g[16n] g2[n] gbuf[8n] deg[n] gcur[nb*16] ebufP[nb*CAP]
//              (~38 MB)

#define D_FEAT 128
#define HIDDEN 16
#define TILE 4096
#define CAP 17408u

__device__ inline float bf2f(unsigned short u) {
    union { unsigned x; float f; } t; t.x = ((unsigned)u) << 16; return t.f;
}

__global__ __launch_bounds__(256) void k_init(float* xe, unsigned* gcur, int n, int nb) {
    int t = blockIdx.x * 256 + threadIdx.x;
    if (t < n) xe[t] = 0.f;
    if (t < nb) gcur[t * 16] = (unsigned)t * CAP;
}

// Fused: load row/col/ea; xe wave segmented scan (rows sorted); LDS bucket
// hist; wave-based block scan (2 barriers); claim padded-bucket regions;
// stage bucket-ordered in LDS; coalesced run writes.
__global__ __launch_bounds__(512) void k_sortplace(const int* __restrict__ row,
                                                   const int* __restrict__ col,
                                                   const float* __restrict__ ea,
                                                   float* __restrict__ xe,
                                                   unsigned* __restrict__ gcur,
                                                   unsigned* __restrict__ ebufP,
                                                   int ne, int nb) {
    __shared__ unsigned stage[TILE];
    __shared__ unsigned short sbuck[TILE];
    __shared__ unsigned h[512], base_[512], cursor[512], gb_[512];
    __shared__ unsigned wsum[8];
    int tid = threadIdx.x;
    int lane = tid & 63;
    int w = tid >> 6;
    int tile0 = blockIdx.x * TILE;
    int cnt_t = min(TILE, ne - tile0);
    h[tid] = 0u;
    __syncthreads();
    int rr[8], cc[8];
    float aa[8];
    #pragma unroll
    for (int k = 0; k < 8; ++k) {
        int e = tile0 + tid + k * 512;
        if (e < ne) {
            rr[k] = row[e]; cc[k] = col[e]; aa[k] = ea[e];
            atomicAdd(&h[cc[k] >> 8], 1u);
        } else { rr[k] = -1; cc[k] = 0; aa[k] = 0.f; }
    }
    // xe segmented scan per 64-edge wave window (rows sorted globally).
    #pragma unroll
    for (int k = 0; k < 8; ++k) {
        int r = rr[k];
        float a = aa[k];
        #pragma unroll
        for (int d = 1; d < 64; d <<= 1) {
            float up = __shfl_up(a, d);
            int  rup = __shfl_up(r, d);
            if (lane >= d && rup == r) a += up;
        }
        int rdn = __shfl_down(r, 1);
        bool tail = (lane == 63) || (rdn != r);
        if (r >= 0 && tail) unsafeAtomicAdd(&xe[r], a);
    }
    __syncthreads();
    // Wave-level inclusive scan of h[512] -> exclusive prefix, 2 barriers.
    unsigned hv = h[tid];
    unsigned s = hv;
    #pragma unroll
    for (int d = 1; d < 64; d <<= 1) {
        unsigned u = __shfl_up(s, d);
        if (lane >= d) s += u;
    }
    if (lane == 63) wsum[w] = s;
    __syncthreads();
    unsigned woff = 0;
    #pragma unroll
    for (int i = 0; i < 8; ++i) woff += (i < w) ? wsum[i] : 0u;
    unsigned ex = s + woff - hv;
    base_[tid] = ex;
    cursor[tid] = ex;
    if (tid < nb && hv) gb_[tid] = atomicAdd(&gcur[tid * 16], hv);
    __syncthreads();
    #pragma unroll
    for (int k = 0; k < 8; ++k) {
        if (rr[k] >= 0) {
            int b = cc[k] >> 8;
            unsigned p = atomicAdd(&cursor[b], 1u);
            stage[p] = (((unsigned)(cc[k] & 255)) << 24) | (unsigned)rr[k];
            sbuck[p] = (unsigned short)b;
        }
    }
    __syncthreads();
    for (int t = tid; t < cnt_t; t += 512) {
        unsigned b = sbuck[t];
        unsigned pos = gb_[b] + ((unsigned)t - base_[b]);
        if (pos < (b + 1u) * CAP) ebufP[pos] = stage[t];
    }
}

// Per-bucket exact-node degree via LDS INT histogram (proven-fast pattern);
// coalesced deg write.
__global__ __launch_bounds__(512) void k_deghist(const unsigned* __restrict__ gcur,
                                                 const unsigned* __restrict__ ebufP,
                                                 unsigned* __restrict__ deg, int n) {
    __shared__ unsigned dg[256];
    int tid = threadIdx.x, b = blockIdx.x;
    if (tid < 256) dg[tid] = 0u;
    __syncthreads();
    unsigned base = (unsigned)b * CAP;
    unsigned m = min(gcur[b * 16] - base, CAP);
    unsigned i = tid;
    for (; i + 1536 < m; i += 2048) {
        unsigned pk0 = ebufP[base + i];
        unsigned pk1 = ebufP[base + i + 512];
        unsigned pk2 = ebufP[base + i + 1024];
        unsigned pk3 = ebufP[base + i + 1536];
        atomicAdd(&dg[pk0 >> 24], 1u);
        atomicAdd(&dg[pk1 >> 24], 1u);
        atomicAdd(&dg[pk2 >> 24], 1u);
        atomicAdd(&dg[pk3 >> 24], 1u);
    }
    for (; i < m; i += 512) atomicAdd(&dg[ebufP[base + i] >> 24], 1u);
    __syncthreads();
    if (tid < 256) {
        int v = b * 256 + tid;
        if (v < n) deg[v] = dg[tid];
    }
}

// g[i][j] = (sum_k x[i][k]*W1[k][j] + xe[i]*W1[128][j]) * rsqrt(deg[i]+1)
// W transposed in LDS (stride 132) -> b128 weight reads.
// Writes fp32 g (self-term) and bf16 gbuf (gather copy, RNE).
__global__ __launch_bounds__(256) void k_gemm1(const float* __restrict__ x,
                                               const float* __restrict__ xe,
                                               const unsigned* __restrict__ deg,
                                               const float* __restrict__ W1,
                                               float* __restrict__ g,
                                               unsigned short* __restrict__ gb, int n) {
    __shared__ float WsT[16 * 132];   // WsT[j*132 + k] = W1[k*16 + j], k=0..128
    __shared__ float xs[64 * 132];
    int tid = threadIdx.x;
    for (int idx = tid; idx < 129 * 16; idx += 256) {
        int k = idx >> 4, j = idx & 15;
        WsT[j * 132 + k] = W1[idx];
    }
    int n0 = blockIdx.x * 64;
    const float4* x4 = (const float4*)x;
    for (int idx = tid; idx < 64 * 32; idx += 256) {
        int r = idx >> 5, c = idx & 31;
        float4 v = (n0 + r < n) ? x4[(size_t)(n0 + r) * 32 + c]
                                : make_float4(0.f, 0.f, 0.f, 0.f);
        *(float4*)&xs[r * 132 + c * 4] = v;
    }
    if (tid < 64) {
        int r = tid;
        xs[r * 132 + 128] = (n0 + r < n) ? xe[n0 + r] : 0.f;
    }
    __syncthreads();
    int j  = tid & 15;
    int nb = tid >> 4;
    const float* wrow = &WsT[j * 132];
    for (int rep = 0; rep < 4; ++rep) {
        int nl = nb + (rep << 4);
        int node = n0 + nl;
        const float* xrow = &xs[nl * 132];
        float acc = 0.f;
        #pragma unroll
        for (int k = 0; k < 128; k += 4) {
            float4 xv = *(const float4*)&xrow[k];
            float4 wv = *(const float4*)&wrow[k];
            acc += xv.x * wv.x;
            acc += xv.y * wv.y;
            acc += xv.z * wv.z;
            acc += xv.w * wv.w;
        }
        acc += xrow[128] * wrow[128];
        if (node < n) {
            float v = acc * rsqrtf((float)deg[node] + 1.0f);
            g[(size_t)node * 16 + j] = v;
            union { float f; unsigned u; } cv; cv.f = v;
            unsigned r16 = (cv.u + 0x7FFFu + ((cv.u >> 16) & 1u)) >> 16;
            gb[(size_t)node * 16 + j] = (unsigned short)r16;
        }
    }
}

// Layer-1 agg per bucket: deg-scan -> per-node start; one ebufP pass
// scatters rows into sorted[] (int LDS cursor atomics); then 16-lane/node
// register walk: lane u=tid&3 owns features 4u..4u+3 (uint2 gather),
// quarter=(tid>>2)&3 splits edges 4-way; shfl_xor(4,8) combines. Fused
// epilogue.
__global__ __launch_bounds__(512) void k_agg1s(const unsigned* __restrict__ gcur,
                                               const unsigned* __restrict__ ebufP,
                                               const unsigned* __restrict__ deg,
                                               const unsigned* __restrict__ gu,
                                               const float* __restrict__ g,
                                               const float* __restrict__ b1,
                                               const float* __restrict__ W2,
                                               float* __restrict__ g2, int n) {
    __shared__ unsigned sorted[CAP];
    __shared__ unsigned dg[256], st[256], cur[256];
    __shared__ unsigned wsum[4];
    int tid = threadIdx.x, b = blockIdx.x, lane = tid & 63;
    unsigned base = (unsigned)b * CAP;
    unsigned m = min(gcur[b * 16] - base, CAP);
    unsigned dval = 0, s = 0;
    if (tid < 256) {
        int v = b * 256 + tid;
        dval = (v < n) ? deg[v] : 0u;
        dg[tid] = dval;
        s = dval;
        #pragma unroll
        for (int d = 1; d < 64; d <<= 1) {
            unsigned uu = __shfl_up(s, d);
            if (lane >= d) s += uu;
        }
        if (lane == 63) wsum[tid >> 6] = s;
    }
    __syncthreads();
    if (tid < 256) {
        int w = tid >> 6;
        unsigned woff = 0;
        #pragma unroll
        for (int i = 0; i < 4; ++i) woff += (i < w) ? wsum[i] : 0u;
        unsigned ex = s + woff - dval;
        st[tid] = ex;
        cur[tid] = ex;
    }
    __syncthreads();
    unsigned i = tid;
    for (; i + 1536 < m; i += 2048) {
        unsigned pk0 = ebufP[base + i];
        unsigned pk1 = ebufP[base + i + 512];
        unsigned pk2 = ebufP[base + i + 1024];
        unsigned pk3 = ebufP[base + i + 1536];
        unsigned p0 = atomicAdd(&cur[pk0 >> 24], 1u);
        unsigned p1 = atomicAdd(&cur[pk1 >> 24], 1u);
        unsigned p2 = atomicAdd(&cur[pk2 >> 24], 1u);
        unsigned p3 = atomicAdd(&cur[pk3 >> 24], 1u);
        if (p0 < CAP) sorted[p0] = pk0 & 0xFFFFFFu;
        if (p1 < CAP) sorted[p1] = pk1 & 0xFFFFFFu;
        if (p2 < CAP) sorted[p2] = pk2 & 0xFFFFFFu;
        if (p3 < CAP) sorted[p3] = pk3 & 0xFFFFFFu;
    }
    for (; i < m; i += 512) {
        unsigned pk = ebufP[base + i];
        unsigned p = atomicAdd(&cur[pk >> 24], 1u);
        if (p < CAP) sorted[p] = pk & 0xFFFFFFu;
    }
    __syncthreads();
    const uint2* gu2 = (const uint2*)gu;
    int grp = tid >> 4;
    int u = tid & 3;
    int quarter = (tid >> 2) & 3;
    float4 bb = ((const float4*)b1)[u];
    float4 ww = ((const float4*)W2)[u];
    for (int it = 0; it < 8; ++it) {
        int c = it * 32 + grp;
        int v = b * 256 + c;
        if (v >= n) break;
        unsigned s0 = st[c], e0 = s0 + dg[c];
        float a0 = 0.f, a1 = 0.f, a2 = 0.f, a3 = 0.f;
        float c0 = 0.f, c1 = 0.f, c2 = 0.f, c3 = 0.f;
        unsigned q = s0 + quarter;
        for (; q + 4 < e0; q += 8) {
            unsigned r0 = sorted[q], r1 = sorted[q + 4];
            uint2 w0 = gu2[(size_t)r0 * 4 + u];
            uint2 w1 = gu2[(size_t)r1 * 4 + u];
            a0 += bf2f((unsigned short)w0.x); a1 += bf2f((unsigned short)(w0.x >> 16));
            a2 += bf2f((unsigned short)w0.y); a3 += bf2f((unsigned short)(w0.y >> 16));
            c0 += bf2f((unsigned short)w1.x); c1 += bf2f((unsigned short)(w1.x >> 16));
            c2 += bf2f((unsigned short)w1.y); c3 += bf2f((unsigned short)(w1.y >> 16));
        }
        for (; q < e0; q += 4) {
            uint2 w0 = gu2[(size_t)sorted[q] * 4 + u];
            a0 += bf2f((unsigned short)w0.x); a1 += bf2f((unsigned short)(w0.x >> 16));
            a2 += bf2f((unsigned short)w0.y); a3 += bf2f((unsigned short)(w0.y >> 16));
        }
        a0 += c0; a1 += c1; a2 += c2; a3 += c3;
        a0 += __shfl_xor(a0, 4, 16); a0 += __shfl_xor(a0, 8, 16);
        a1 += __shfl_xor(a1, 4, 16); a1 += __shfl_xor(a1, 8, 16);
        a2 += __shfl_xor(a2, 4, 16); a2 += __shfl_xor(a2, 8, 16);
        a3 += __shfl_xor(a3, 4, 16); a3 += __shfl_xor(a3, 8, 16);
        float di = rsqrtf((float)dg[c] + 1.0f);
        float4 gs = ((const float4*)g)[(size_t)v * 4 + u];
        float v0 = fmaxf(di * (gs.x + a0) + bb.x, 0.f);
        float v1 = fmaxf(di * (gs.y + a1) + bb.y, 0.f);
        float v2 = fmaxf(di * (gs.z + a2) + bb.z, 0.f);
        float v3 = fmaxf(di * (gs.w + a3) + bb.w, 0.f);
        float prd = v0 * ww.x + v1 * ww.y + v2 * ww.z + v3 * ww.w;
        prd += __shfl_down(prd, 2, 4);
        prd += __shfl_down(prd, 1, 4);
        if ((tid & 15) == 0) g2[v] = prd * di;
    }
}

// Layer-2 agg per bucket: same sort prologue; 2-lane/node scalar walk over
// L2-hot g2 gathers; fused output epilogue.
__global__ __launch_bounds__(512) void k_agg2s(const unsigned* __restrict__ gcur,
                                               const unsigned* __restrict__ ebufP,
                                               const unsigned* __restrict__ deg,
                                               const float* __restrict__ g2,
                                               const float* __restrict__ b2,
                                               float* __restrict__ out, int n) {
    __shared__ unsigned sorted[CAP];
    __shared__ unsigned dg[256], st[256], cur[256];
    __shared__ unsigned wsum[4];
    int tid = threadIdx.x, b = blockIdx.x, lane = tid & 63;
    unsigned base = (unsigned)b * CAP;
    unsigned m = min(gcur[b * 16] - base, CAP);
    unsigned dval = 0, s = 0;
    if (tid < 256) {
        int v = b * 256 + tid;
        dval = (v < n) ? deg[v] : 0u;
        dg[tid] = dval;
        s = dval;
        #pragma unroll
        for (int d = 1; d < 64; d <<= 1) {
            unsigned uu = __shfl_up(s, d);
            if (lane >= d) s += uu;
        }
        if (lane == 63) wsum[tid >> 6] = s;
    }
    __syncthreads();
    if (tid < 256) {
        int w = tid >> 6;
        unsigned woff = 0;
        #pragma unroll
        for (int i = 0; i < 4; ++i) woff += (i < w) ? wsum[i] : 0u;
        unsigned ex = s + woff - dval;
        st[tid] = ex;
        cur[tid] = ex;
    }
    __syncthreads();
    unsigned i = tid;
    for (; i + 1536 < m; i += 2048) {
        unsigned pk0 = ebufP[base + i];
        unsigned pk1 = ebufP[base + i + 512];
        unsigned pk2 = ebufP[base + i + 1024];
        unsigned pk3 = ebufP[base + i + 1536];
        unsigned p0 = atomicAdd(&cur[pk0 >> 24], 1u);
        unsigned p1 = atomicAdd(&cur[pk1 >> 24], 1u);
        unsigned p2 = atomicAdd(&cur[pk2 >> 24], 1u);
        unsigned p3 = atomicAdd(&cur[pk3 >> 24], 1u);
        if (p0 < CAP) sorted[p0] = pk0 & 0xFFFFFFu;
        if (p1 < CAP) sorted[p1] = pk1 & 0xFFFFFFu;
        if (p2 < CAP) sorted[p2] = pk2 & 0xFFFFFFu;
        if (p3 < CAP) sorted[p3] = pk3 & 0xFFFFFFu;
    }
    for (; i < m; i += 512) {
        unsigned pk = ebufP[base + i];
        unsigned p = atomicAdd(&cur[pk >> 24], 1u);
        if (p < CAP) sorted[p] = pk & 0xFFFFFFu;
    }
    __syncthreads();
    int c = tid >> 1, half = tid & 1;
    int v = b * 256 + c;
    float a = 0.f;
    unsigned s0 = st[c], e0 = s0 + dg[c];
    unsigned q = s0 + half;
    for (; q + 2 < e0; q += 4) {
        a += g2[sorted[q]];
        a += g2[sorted[q + 2]];
    }
    if (q < e0) a += g2[sorted[q]];
    a += __shfl_xor(a, 1, 2);
    if (half == 0 && v < n) {
        float di = rsqrtf((float)dg[c] + 1.0f);
        out[v] = di * (g2[v] + a) + b2[0];
    }
}

extern "C" void kernel_launch(void* const* d_in, const int* in_sizes, int n_in,
                              void* d_out, int out_size, void* d_ws, size_t ws_size,
                              hipStream_t stream) {
    const float* x   = (const float*)d_in[0];
    const float* ea  = (const float*)d_in[1];
    const int*   row = (const int*)d_in[2];
    const int*   col = (const int*)d_in[3];
    const float* W1  = (const float*)d_in[4];
    const float* b1  = (const float*)d_in[5];
    const float* W2  = (const float*)d_in[6];
    const float* b2  = (const float*)d_in[7];
    float* out = (float*)d_out;

    int n  = in_sizes[0] / D_FEAT;   // 100000
    int ne = in_sizes[2];            // 6400000
    int nb = (n + 255) >> 8;         // 391 buckets of 256 nodes

    float* ws   = (float*)d_ws;
    float* xe   = ws;                      // n
    float* g    = ws + (size_t)n;          // 16n
    float* g2   = ws + (size_t)17 * n;     // n
    unsigned short* gbuf = (unsigned short*)(ws + (size_t)18 * n);  // 16n ushort = 8n floats
    unsigned* deg  = (unsigned*)(ws + (size_t)26 * n);  // n
    unsigned* gcur = deg + (size_t)n;                   // nb*16
    unsigned* ebufP = gcur + (size_t)nb * 16;           // nb*CAP

    dim3 blk(256);
    int g_node = (n + 255) / 256;
    int g_tile = (ne + TILE - 1) / TILE;
    int g_gemm = (n + 63) / 64;

    k_init<<<g_node, blk, 0, stream>>>(xe, gcur, n, nb);
    k_sortplace<<<g_tile, 512, 0, stream>>>(row, col, ea, xe, gcur, ebufP, ne, nb);
    k_deghist<<<nb, 512, 0, stream>>>(gcur, ebufP, deg, n);
    k_gemm1<<<g_gemm, blk, 0, stream>>>(x, xe, deg, W1, g, gbuf, n);
    k_agg1s<<<nb, 512, 0, stream>>>(gcur, ebufP, deg, (const unsigned*)gbuf, g, b1, W2, g2, n);
    k_agg2s<<<nb, 512, 0, stream>>>(gcur, ebufP, deg, g2, b2, out, n);
}